// Round 13
// baseline (286.560 us; speedup 1.0000x reference)
//
#include <hip/hip_runtime.h>

typedef float f32x4 __attribute__((ext_vector_type(4)));

// db4 reconstruction filters
#define G00 0.23037781330885523f
#define G01 0.7148465705525415f
#define G02 0.6308807679295904f
#define G03 -0.02798376941698385f
#define G04 -0.18703481171888114f
#define G05 0.030841381835986965f
#define G06 0.032883011666982945f
#define G07 -0.010597401784997278f

#define G10 -0.010597401784997278f
#define G11 -0.032883011666982945f
#define G12 0.030841381835986965f
#define G13 0.18703481171888114f
#define G14 -0.02798376941698385f
#define G15 -0.6308807679295904f
#define G16 0.7148465705525415f
#define G17 -0.23037781330885523f

// ===========================================================================
// Level-1 path (N=64): R7 kernel, unchanged (verified best).
// ===========================================================================
template<int LOGN, bool NT>
__device__ __forceinline__ void phaseBC(f32x4* smem, float* __restrict__ out,
                                        int b, int d, int tile, int tid)
{
    constexpr int N = 1 << LOGN;
    constexpr int N4 = N / 4;
    constexpr int LOGN4 = LOGN - 2;
    constexpr int BELEMS = 2 * 32 * N4;
    constexpr int BITER  = BELEMS / 512;

    f32x4 ureg[BITER];
    #pragma unroll
    for (int it = 0; it < BITER; ++it) {
        int e = it * 512 + tid;
        int w4   = e & (N4 - 1);
        int rest = e >> LOGN4;
        int hl   = rest & 31;
        int qq   = rest >> 5;
        int ml = hl >> 1, pp = hl & 1;
        int ro = ml + pp + 3;
        float b0c = pp ? G00 : G01, b1c = pp ? G02 : G03;
        float b2c = pp ? G04 : G05, b3c = pp ? G06 : G07;
        float d0c = pp ? G10 : G11, d1c = pp ? G12 : G13;
        float d2c = pp ? G14 : G15, d3c = pp ? G16 : G17;
        int s0 = 2 * qq, s1 = s0 + 1;
        ureg[it] = b0c * smem[(s0 * 20 + ro    ) * N4 + w4]
                 + b1c * smem[(s0 * 20 + ro - 1) * N4 + w4]
                 + b2c * smem[(s0 * 20 + ro - 2) * N4 + w4]
                 + b3c * smem[(s0 * 20 + ro - 3) * N4 + w4]
                 + d0c * smem[(s1 * 20 + ro    ) * N4 + w4]
                 + d1c * smem[(s1 * 20 + ro - 1) * N4 + w4]
                 + d2c * smem[(s1 * 20 + ro - 2) * N4 + w4]
                 + d3c * smem[(s1 * 20 + ro - 3) * N4 + w4];
    }
    __syncthreads();
    #pragma unroll
    for (int it = 0; it < BITER; ++it) {
        smem[it * 512 + tid] = ureg[it];
    }
    __syncthreads();

    const float* ulf = (const float*)smem;
    float* orow_base = out + (((size_t)b * (2 * N) + d) * (2 * N) + (size_t)32 * tile) * (2 * N);
    for (int e = tid; e < 32 * (N / 2); e += 512) {
        int mw2 = e & (N / 2 - 1);
        int hl  = e >> (LOGN - 1);
        int mw  = mw2 * 2;
        const float* u0 = ulf + (size_t)hl * N;
        const float* u1 = ulf + (size_t)(32 + hl) * N;
        int mm2 = (mw - 2) & (N - 1), mm1 = (mw - 1) & (N - 1);
        int mp1 = (mw + 1) & (N - 1), mp2 = (mw + 2) & (N - 1), mp3 = (mw + 3) & (N - 1);
        float u0m2 = u0[mm2], u0m1 = u0[mm1], u00 = u0[mw];
        float u0p1 = u0[mp1], u0p2 = u0[mp2], u0p3 = u0[mp3];
        float u1m2 = u1[mm2], u1m1 = u1[mm1], u10 = u1[mw];
        float u1p1 = u1[mp1], u1p2 = u1[mp2], u1p3 = u1[mp3];
        f32x4 o;
        o.x = G01*u0p1 + G03*u00  + G05*u0m1 + G07*u0m2
            + G11*u1p1 + G13*u10  + G15*u1m1 + G17*u1m2;
        o.y = G00*u0p2 + G02*u0p1 + G04*u00  + G06*u0m1
            + G10*u1p2 + G12*u1p1 + G14*u10  + G16*u1m1;
        o.z = G01*u0p2 + G03*u0p1 + G05*u00  + G07*u0m1
            + G11*u1p2 + G13*u1p1 + G15*u10  + G17*u1m1;
        o.w = G00*u0p3 + G02*u0p2 + G04*u0p1 + G06*u00
            + G10*u1p3 + G12*u1p2 + G14*u1p1 + G16*u10;
        f32x4* dst = (f32x4*)(orow_base + (size_t)hl * (2 * N)) + mw2;
        if (NT) __builtin_nontemporal_store(o, dst);
        else    *dst = o;
    }
}

template<int LOGN, bool NT>
__global__ __launch_bounds__(512) void idwt3_fused2_k(
    const float* __restrict__ ll, const float* __restrict__ yh,
    float* __restrict__ out, int b0)
{
    constexpr int N = 1 << LOGN;
    constexpr int N4 = N / 4;
    constexpr int LOGN4 = LOGN - 2;
    constexpr int NN = N * N;
    constexpr size_t V = (size_t)N * N * N;
    constexpr int AELEMS = 4 * 20 * N4;
    constexpr int AITER  = (AELEMS + 511) / 512;

    __shared__ f32x4 smem[AELEMS];

    const int tid  = threadIdx.x;
    const int tile = blockIdx.x;
    const int mD   = blockIdx.y;
    const int b    = b0 + (int)blockIdx.z;

    const size_t q0 = (size_t)((mD - 2 + N) & (N - 1)) * NN;
    const size_t q1 = (size_t)((mD - 1 + N) & (N - 1)) * NN;
    const size_t q2 = (size_t)( mD                    ) * NN;
    const size_t q3 = (size_t)((mD + 1) & (N - 1)) * NN;
    const size_t q4 = (size_t)((mD + 2) & (N - 1)) * NN;

    const int h0in = 16 * tile - 2;
    const float* llb = ll + (size_t)b * V;
    const float* yb  = yh + (size_t)b * 7 * V;

    f32x4 treg[AITER];
    #pragma unroll
    for (int it = 0; it < AITER; ++it) {
        int e = it * 512 + tid;
        if (AELEMS % 512 != 0 && e >= AELEMS) continue;
        int w4 = e & (N4 - 1);
        int x  = e >> LOGN4;
        int pr = x / 20;
        int r  = x - 20 * pr;
        int hr = h0in + r;
        if (hr < 0) hr += N;
        if (hr >= N) hr -= N;
        const float* lo_base = (pr == 0) ? llb : (yb + (size_t)(2 * pr - 1) * V);
        const float* hi_base = yb + (size_t)(2 * pr) * V;
        int off = hr * N + w4 * 4;
        const float* lp = lo_base + off;
        const float* hp = hi_base + off;
        f32x4 Lm2 = *(const f32x4*)(lp + q0);
        f32x4 Lm1 = *(const f32x4*)(lp + q1);
        f32x4 L0c = *(const f32x4*)(lp + q2);
        f32x4 Lp1 = *(const f32x4*)(lp + q3);
        f32x4 Lp2 = *(const f32x4*)(lp + q4);
        f32x4 Hm2 = *(const f32x4*)(hp + q0);
        f32x4 Hm1 = *(const f32x4*)(hp + q1);
        f32x4 H0c = *(const f32x4*)(hp + q2);
        f32x4 Hp1 = *(const f32x4*)(hp + q3);
        f32x4 Hp2 = *(const f32x4*)(hp + q4);
        smem[e] = G01*Lp1 + G03*L0c + G05*Lm1 + G07*Lm2
                + G11*Hp1 + G13*H0c + G15*Hm1 + G17*Hm2;
        treg[it] = G00*Lp2 + G02*Lp1 + G04*L0c + G06*Lm1
                 + G10*Hp2 + G12*Hp1 + G14*H0c + G16*Hm1;
    }
    __syncthreads();

    phaseBC<LOGN, NT>(smem, out, b, 2 * mD, tile, tid);
    __syncthreads();

    #pragma unroll
    for (int it = 0; it < AITER; ++it) {
        int e = it * 512 + tid;
        if (AELEMS % 512 != 0 && e >= AELEMS) continue;
        smem[e] = treg[it];
    }
    __syncthreads();

    phaseBC<LOGN, NT>(smem, out, b, 2 * mD + 1, tile, tid);
}

// ===========================================================================
// Level-2 (N=128): persistent double-buffered pipeline.
// One block per (mD, b); iterates all 8 h-tiles. While tile t's B/C chains
// run from smem[t&1], Phase A of tile t+1 (5 batches of 10 loads) is issued/
// consumed between the existing barriers into smem[(t&1)^1] + tN registers.
// B = sliding-window (R8/R9 verified), C = b128-window (R12 verified).
// ===========================================================================
__device__ __forceinline__ void bphase_l2(const f32x4* buf, int tid,
                                          f32x4& U0, f32x4& U1, f32x4& U2, f32x4& U3)
{
    const int w4c = tid & 31;
    const int qq  = (tid >> 5) & 1;
    const int s   = tid >> 6;                       // [0,8)
    const f32x4* t0 = buf + ((2 * qq) * 20 + 2 * s) * 32 + w4c;   // lo tile
    const f32x4* t1 = t0 + 20 * 32;                               // hi tile
    f32x4 r0 = t0[0],   r1 = t0[32],  r2 = t0[64];
    f32x4 r3 = t0[96],  r4 = t0[128], r5 = t0[160];
    f32x4 e0 = t1[0],   e1 = t1[32],  e2 = t1[64];
    f32x4 e3 = t1[96],  e4 = t1[128], e5 = t1[160];
    U0 = G01*r3 + G03*r2 + G05*r1 + G07*r0 + G11*e3 + G13*e2 + G15*e1 + G17*e0;
    U1 = G00*r4 + G02*r3 + G04*r2 + G06*r1 + G10*e4 + G12*e3 + G14*e2 + G16*e1;
    U2 = G01*r4 + G03*r3 + G05*r2 + G07*r1 + G11*e4 + G13*e3 + G15*e2 + G17*e1;
    U3 = G00*r5 + G02*r4 + G04*r3 + G06*r2 + G10*e5 + G12*e4 + G14*e3 + G16*e2;
}

__device__ __forceinline__ void ulwrite_l2(f32x4* buf, int tid,
                                           f32x4 U0, f32x4 U1, f32x4 U2, f32x4 U3)
{
    const int w4c = tid & 31;
    const int qq  = (tid >> 5) & 1;
    const int s   = tid >> 6;
    f32x4* ub = buf + ((qq * 32 + 4 * s) * 33 + w4c);
    ub[0]  = U0;
    ub[33] = U1;
    ub[66] = U2;
    ub[99] = U3;
}

__device__ __forceinline__ void cphase_l2(const f32x4* buf, float* orow_base, int tid)
{
    #pragma unroll
    for (int it = 0; it < 4; ++it) {
        int e  = it * 512 + tid;
        int ow = e & 63;
        int hl = e >> 6;
        int odd = ow & 1;
        int i0 = ((2 * ow - 2) & 127) >> 2;
        int i1 = ((2 * ow + 3) & 127) >> 2;
        const f32x4* u0r = buf + (size_t)hl * 33;
        const f32x4* u1r = buf + (size_t)(32 + hl) * 33;
        f32x4 P  = u0r[i0], Q  = u0r[i1];
        f32x4 Pp = u1r[i0], Qp = u1r[i1];
        float w0 = odd ? P[0]  : P[2],  w1 = odd ? P[1]  : P[3];
        float w2 = odd ? P[2]  : Q[0],  w3 = odd ? P[3]  : Q[1];
        float w4 = odd ? Q[0]  : Q[2],  w5 = odd ? Q[1]  : Q[3];
        float x0 = odd ? Pp[0] : Pp[2], x1 = odd ? Pp[1] : Pp[3];
        float x2 = odd ? Pp[2] : Qp[0], x3 = odd ? Pp[3] : Qp[1];
        float x4 = odd ? Qp[0] : Qp[2], x5 = odd ? Qp[1] : Qp[3];
        f32x4 o;
        o[0] = G01*w3 + G03*w2 + G05*w1 + G07*w0
             + G11*x3 + G13*x2 + G15*x1 + G17*x0;
        o[1] = G00*w4 + G02*w3 + G04*w2 + G06*w1
             + G10*x4 + G12*x3 + G14*x2 + G16*x1;
        o[2] = G01*w4 + G03*w3 + G05*w2 + G07*w1
             + G11*x4 + G13*x3 + G15*x2 + G17*x1;
        o[3] = G00*w5 + G02*w4 + G04*w3 + G06*w2
             + G10*x5 + G12*x4 + G14*x3 + G16*x2;
        __builtin_nontemporal_store(o, (f32x4*)(orow_base + (size_t)hl * 256) + ow);
    }
}

// Issue one Phase-A batch (10 f32x4 loads) for tile t, batch k, into A0..A9.
#define AISSUE(t, k) { \
    int x_ = (k) * 16 + xr; int pr_ = x_ / 20; int r_ = x_ - 20 * pr_; \
    int hr_ = 16 * (t) - 2 + r_; if (hr_ < 0) hr_ += 128; if (hr_ >= 128) hr_ -= 128; \
    const float* lo_ = (pr_ == 0) ? llb : (yb + (size_t)(2 * pr_ - 1) * V); \
    const float* hi_ = yb + (size_t)(2 * pr_) * V; \
    const float* lp_ = lo_ + hr_ * 128 + w4c * 4; \
    const float* hp_ = hi_ + hr_ * 128 + w4c * 4; \
    A0 = *(const f32x4*)(lp_ + q0); A1 = *(const f32x4*)(lp_ + q1); \
    A2 = *(const f32x4*)(lp_ + q2); A3 = *(const f32x4*)(lp_ + q3); \
    A4 = *(const f32x4*)(lp_ + q4); \
    A5 = *(const f32x4*)(hp_ + q0); A6 = *(const f32x4*)(hp_ + q1); \
    A7 = *(const f32x4*)(hp_ + q2); A8 = *(const f32x4*)(hp_ + q3); \
    A9 = *(const f32x4*)(hp_ + q4); }

// Consume batch k: p0 t-value -> dstbuf, p1 t-value -> tarr[k] (static k).
#define ACONSUME(k, dstbuf, tarr) { \
    (dstbuf)[(k) * 512 + tid] = G01*A3 + G03*A2 + G05*A1 + G07*A0 \
                              + G11*A8 + G13*A7 + G15*A6 + G17*A5; \
    (tarr)[k]                 = G00*A4 + G02*A3 + G04*A2 + G06*A1 \
                              + G10*A9 + G12*A8 + G14*A7 + G16*A6; }

__global__ __launch_bounds__(512, 2) void idwt3_l2p_k(
    const float* __restrict__ ll, const float* __restrict__ yh,
    float* __restrict__ out)
{
    constexpr int N = 128;
    constexpr int NN = N * N;
    constexpr size_t V = (size_t)N * N * N;

    __shared__ f32x4 smem[2][2560];                 // double-buffered tl/ul

    const int tid = threadIdx.x;
    const int mD  = blockIdx.x;                     // d-pair index [0,128)
    const int b   = blockIdx.y;                     // batch [0,4)

    const size_t q0 = (size_t)((mD - 2 + N) & (N - 1)) * NN;
    const size_t q1 = (size_t)((mD - 1 + N) & (N - 1)) * NN;
    const size_t q2 = (size_t)( mD                    ) * NN;
    const size_t q3 = (size_t)((mD + 1) & (N - 1)) * NN;
    const size_t q4 = (size_t)((mD + 2) & (N - 1)) * NN;

    const float* llb = ll + (size_t)b * V;
    const float* yb  = yh + (size_t)b * 7 * V;
    const int xr  = tid >> 5;
    const int w4c = tid & 31;

    f32x4 tP[5], tN[5];                             // p1 tiles (static idx only)
    f32x4 A0, A1, A2, A3, A4, A5, A6, A7, A8, A9;   // in-flight load batch

    // ---- cold Phase A for tile 0 -> smem[0] + tP
    #pragma unroll
    for (int k = 0; k < 5; ++k) {
        AISSUE(0, k);
        ACONSUME(k, smem[0], tP);
    }
    __syncthreads();

    for (int t = 0; t < 8; ++t) {
        f32x4* buf = smem[t & 1];
        f32x4* nxt = smem[(t & 1) ^ 1];
        const bool pf = (t < 7);
        float* orow0 = out + (((size_t)b * 256 + (size_t)2 * mD) * 256
                              + (size_t)32 * t) * 256;
        float* orow1 = orow0 + 65536;               // d+1 plane

        f32x4 U0, U1, U2, U3;

        // S1: B(parity 0) reads tl(buf); prefetch batch 0 issued first
        if (pf) { AISSUE(t + 1, 0); }
        bphase_l2(buf, tid, U0, U1, U2, U3);
        __syncthreads();                            // tl(buf) reads done
        // S2: ul writes (overlay tl); consume batch 0 -> nxt, issue batch 1
        ulwrite_l2(buf, tid, U0, U1, U2, U3);
        if (pf) { ACONSUME(0, nxt, tN); AISSUE(t + 1, 1); }
        __syncthreads();                            // ul(buf) ready
        // S3: C(parity 0); consume 1, issue 2
        cphase_l2(buf, orow0, tid);
        if (pf) { ACONSUME(1, nxt, tN); AISSUE(t + 1, 2); }
        __syncthreads();                            // ul(buf) reads done
        // S4: swap p1 tile into buf; consume 2, issue 3
        #pragma unroll
        for (int k = 0; k < 5; ++k) buf[k * 512 + tid] = tP[k];
        if (pf) { ACONSUME(2, nxt, tN); AISSUE(t + 1, 3); }
        __syncthreads();                            // tl(buf)=p1 ready
        // S5: B(parity 1)
        bphase_l2(buf, tid, U0, U1, U2, U3);
        __syncthreads();
        // S6: ul writes; consume 3, issue 4
        ulwrite_l2(buf, tid, U0, U1, U2, U3);
        if (pf) { ACONSUME(3, nxt, tN); AISSUE(t + 1, 4); }
        __syncthreads();
        // S7: C(parity 1); consume 4; roll tN -> tP
        cphase_l2(buf, orow1, tid);
        if (pf) {
            ACONSUME(4, nxt, tN);
            #pragma unroll
            for (int k = 0; k < 5; ++k) tP[k] = tN[k];
        }
        __syncthreads();                            // nxt fully written; buf free
    }
}

// ===========================================================================

extern "C" void kernel_launch(void* const* d_in, const int* in_sizes, int n_in,
                              void* d_out, int out_size, void* d_ws, size_t ws_size,
                              hipStream_t stream)
{
    const float* yl  = (const float*)d_in[0];   // (4,1,64,64,64)
    const float* yh1 = (const float*)d_in[1];   // (4,7,128,128,128)
    const float* yh2 = (const float*)d_in[2];   // (4,7,64,64,64)
    float* outf = (float*)d_out;                // (4,1,256,256,256)
    float* ll1  = (float*)d_ws;                 // (4,128,128,128) scratch

    // Level 1 (n=64 -> 128): R7 kernel, all batches
    idwt3_fused2_k<6, false><<<dim3(4, 64, 4), 512, 0, stream>>>(yl, yh2, ll1, 0);

    // Level 2 (n=128 -> 256): persistent pipelined kernel, 512 blocks = 2/CU
    idwt3_l2p_k<<<dim3(128, 4), 512, 0, stream>>>(ll1, yh1, outf);
}

// Round 14
// 177.084 us; speedup vs baseline: 1.6182x; 1.6182x over previous
//
#include <hip/hip_runtime.h>

typedef float f32x4 __attribute__((ext_vector_type(4)));

// db4 reconstruction filters
#define G00 0.23037781330885523f
#define G01 0.7148465705525415f
#define G02 0.6308807679295904f
#define G03 -0.02798376941698385f
#define G04 -0.18703481171888114f
#define G05 0.030841381835986965f
#define G06 0.032883011666982945f
#define G07 -0.010597401784997278f

#define G10 -0.010597401784997278f
#define G11 -0.032883011666982945f
#define G12 0.030841381835986965f
#define G13 0.18703481171888114f
#define G14 -0.02798376941698385f
#define G15 -0.6308807679295904f
#define G16 0.7148465705525415f
#define G17 -0.23037781330885523f

// ===========================================================================
// Level-1 path (N=64): R7/R12 kernel, unchanged (verified best).
// ===========================================================================
template<int LOGN, bool NT>
__device__ __forceinline__ void phaseBC(f32x4* smem, float* __restrict__ out,
                                        int b, int d, int tile, int tid)
{
    constexpr int N = 1 << LOGN;
    constexpr int N4 = N / 4;
    constexpr int LOGN4 = LOGN - 2;
    constexpr int BELEMS = 2 * 32 * N4;
    constexpr int BITER  = BELEMS / 512;

    f32x4 ureg[BITER];
    #pragma unroll
    for (int it = 0; it < BITER; ++it) {
        int e = it * 512 + tid;
        int w4   = e & (N4 - 1);
        int rest = e >> LOGN4;
        int hl   = rest & 31;
        int qq   = rest >> 5;
        int ml = hl >> 1, pp = hl & 1;
        int ro = ml + pp + 3;
        float b0c = pp ? G00 : G01, b1c = pp ? G02 : G03;
        float b2c = pp ? G04 : G05, b3c = pp ? G06 : G07;
        float d0c = pp ? G10 : G11, d1c = pp ? G12 : G13;
        float d2c = pp ? G14 : G15, d3c = pp ? G16 : G17;
        int s0 = 2 * qq, s1 = s0 + 1;
        ureg[it] = b0c * smem[(s0 * 20 + ro    ) * N4 + w4]
                 + b1c * smem[(s0 * 20 + ro - 1) * N4 + w4]
                 + b2c * smem[(s0 * 20 + ro - 2) * N4 + w4]
                 + b3c * smem[(s0 * 20 + ro - 3) * N4 + w4]
                 + d0c * smem[(s1 * 20 + ro    ) * N4 + w4]
                 + d1c * smem[(s1 * 20 + ro - 1) * N4 + w4]
                 + d2c * smem[(s1 * 20 + ro - 2) * N4 + w4]
                 + d3c * smem[(s1 * 20 + ro - 3) * N4 + w4];
    }
    __syncthreads();
    #pragma unroll
    for (int it = 0; it < BITER; ++it) {
        smem[it * 512 + tid] = ureg[it];
    }
    __syncthreads();

    const float* ulf = (const float*)smem;
    float* orow_base = out + (((size_t)b * (2 * N) + d) * (2 * N) + (size_t)32 * tile) * (2 * N);
    for (int e = tid; e < 32 * (N / 2); e += 512) {
        int mw2 = e & (N / 2 - 1);
        int hl  = e >> (LOGN - 1);
        int mw  = mw2 * 2;
        const float* u0 = ulf + (size_t)hl * N;
        const float* u1 = ulf + (size_t)(32 + hl) * N;
        int mm2 = (mw - 2) & (N - 1), mm1 = (mw - 1) & (N - 1);
        int mp1 = (mw + 1) & (N - 1), mp2 = (mw + 2) & (N - 1), mp3 = (mw + 3) & (N - 1);
        float u0m2 = u0[mm2], u0m1 = u0[mm1], u00 = u0[mw];
        float u0p1 = u0[mp1], u0p2 = u0[mp2], u0p3 = u0[mp3];
        float u1m2 = u1[mm2], u1m1 = u1[mm1], u10 = u1[mw];
        float u1p1 = u1[mp1], u1p2 = u1[mp2], u1p3 = u1[mp3];
        f32x4 o;
        o.x = G01*u0p1 + G03*u00  + G05*u0m1 + G07*u0m2
            + G11*u1p1 + G13*u10  + G15*u1m1 + G17*u1m2;
        o.y = G00*u0p2 + G02*u0p1 + G04*u00  + G06*u0m1
            + G10*u1p2 + G12*u1p1 + G14*u10  + G16*u1m1;
        o.z = G01*u0p2 + G03*u0p1 + G05*u00  + G07*u0m1
            + G11*u1p2 + G13*u1p1 + G15*u10  + G17*u1m1;
        o.w = G00*u0p3 + G02*u0p2 + G04*u0p1 + G06*u00
            + G10*u1p3 + G12*u1p2 + G14*u1p1 + G16*u10;
        f32x4* dst = (f32x4*)(orow_base + (size_t)hl * (2 * N)) + mw2;
        if (NT) __builtin_nontemporal_store(o, dst);
        else    *dst = o;
    }
}

template<int LOGN, bool NT>
__global__ __launch_bounds__(512) void idwt3_fused2_k(
    const float* __restrict__ ll, const float* __restrict__ yh,
    float* __restrict__ out, int b0)
{
    constexpr int N = 1 << LOGN;
    constexpr int N4 = N / 4;
    constexpr int LOGN4 = LOGN - 2;
    constexpr int NN = N * N;
    constexpr size_t V = (size_t)N * N * N;
    constexpr int AELEMS = 4 * 20 * N4;
    constexpr int AITER  = (AELEMS + 511) / 512;

    __shared__ f32x4 smem[AELEMS];

    const int tid  = threadIdx.x;
    const int tile = blockIdx.x;
    const int mD   = blockIdx.y;
    const int b    = b0 + (int)blockIdx.z;

    const size_t q0 = (size_t)((mD - 2 + N) & (N - 1)) * NN;
    const size_t q1 = (size_t)((mD - 1 + N) & (N - 1)) * NN;
    const size_t q2 = (size_t)( mD                    ) * NN;
    const size_t q3 = (size_t)((mD + 1) & (N - 1)) * NN;
    const size_t q4 = (size_t)((mD + 2) & (N - 1)) * NN;

    const int h0in = 16 * tile - 2;
    const float* llb = ll + (size_t)b * V;
    const float* yb  = yh + (size_t)b * 7 * V;

    f32x4 treg[AITER];
    #pragma unroll
    for (int it = 0; it < AITER; ++it) {
        int e = it * 512 + tid;
        if (AELEMS % 512 != 0 && e >= AELEMS) continue;
        int w4 = e & (N4 - 1);
        int x  = e >> LOGN4;
        int pr = x / 20;
        int r  = x - 20 * pr;
        int hr = h0in + r;
        if (hr < 0) hr += N;
        if (hr >= N) hr -= N;
        const float* lo_base = (pr == 0) ? llb : (yb + (size_t)(2 * pr - 1) * V);
        const float* hi_base = yb + (size_t)(2 * pr) * V;
        int off = hr * N + w4 * 4;
        const float* lp = lo_base + off;
        const float* hp = hi_base + off;
        f32x4 Lm2 = *(const f32x4*)(lp + q0);
        f32x4 Lm1 = *(const f32x4*)(lp + q1);
        f32x4 L0c = *(const f32x4*)(lp + q2);
        f32x4 Lp1 = *(const f32x4*)(lp + q3);
        f32x4 Lp2 = *(const f32x4*)(lp + q4);
        f32x4 Hm2 = *(const f32x4*)(hp + q0);
        f32x4 Hm1 = *(const f32x4*)(hp + q1);
        f32x4 H0c = *(const f32x4*)(hp + q2);
        f32x4 Hp1 = *(const f32x4*)(hp + q3);
        f32x4 Hp2 = *(const f32x4*)(hp + q4);
        smem[e] = G01*Lp1 + G03*L0c + G05*Lm1 + G07*Lm2
                + G11*Hp1 + G13*H0c + G15*Hm1 + G17*Hm2;
        treg[it] = G00*Lp2 + G02*Lp1 + G04*L0c + G06*Lm1
                 + G10*Hp2 + G12*Hp1 + G14*H0c + G16*Hm1;
    }
    __syncthreads();

    phaseBC<LOGN, NT>(smem, out, b, 2 * mD, tile, tid);
    __syncthreads();

    #pragma unroll
    for (int it = 0; it < AITER; ++it) {
        int e = it * 512 + tid;
        if (AELEMS % 512 != 0 && e >= AELEMS) continue;
        smem[e] = treg[it];
    }
    __syncthreads();

    phaseBC<LOGN, NT>(smem, out, b, 2 * mD + 1, tile, tid);
}

// ===========================================================================
// Level-2 path (N=128): R12 structure + 2-deep software-pipelined Phase A
// (two named 10-register load batches; 20 f32x4 loads always in flight).
// ===========================================================================
__device__ __forceinline__ void phaseBC_l2(f32x4* smem, float* __restrict__ out,
                                           int b, int d, int tile, int tid)
{
    // ---- Phase B: thread = (s, qq, w4); 4 h-outputs from 12 b128 reads.
    {
        const int w4 = tid & 31;
        const int qq = (tid >> 5) & 1;
        const int s  = tid >> 6;                     // [0,8)
        const f32x4* t0 = smem + ((2 * qq) * 20 + 2 * s) * 32 + w4;   // lo tile
        const f32x4* t1 = t0 + 20 * 32;                               // hi tile
        f32x4 r0 = t0[0],   r1 = t0[32],  r2 = t0[64];
        f32x4 r3 = t0[96],  r4 = t0[128], r5 = t0[160];
        f32x4 e0 = t1[0],   e1 = t1[32],  e2 = t1[64];
        f32x4 e3 = t1[96],  e4 = t1[128], e5 = t1[160];
        f32x4 u0r = G01*r3 + G03*r2 + G05*r1 + G07*r0
                  + G11*e3 + G13*e2 + G15*e1 + G17*e0;
        f32x4 u1r = G00*r4 + G02*r3 + G04*r2 + G06*r1
                  + G10*e4 + G12*e3 + G14*e2 + G16*e1;
        f32x4 u2r = G01*r4 + G03*r3 + G05*r2 + G07*r1
                  + G11*e4 + G13*e3 + G15*e2 + G17*e1;
        f32x4 u3r = G00*r5 + G02*r4 + G04*r3 + G06*r2
                  + G10*e5 + G12*e4 + G14*e3 + G16*e2;
        __syncthreads();                             // all tl reads complete
        f32x4* ub = smem + ((qq * 32 + 4 * s) * 33 + w4);
        ub[0]  = u0r;
        ub[33] = u1r;
        ub[66] = u2r;
        ub[99] = u3r;
    }
    __syncthreads();

    // ---- Phase C: b128 window reads (2 f32x4 per subband) + parity selects.
    float* orow_base = out + (((size_t)b * 256 + d) * 256 + (size_t)32 * tile) * 256;
    #pragma unroll
    for (int it = 0; it < 4; ++it) {
        int e  = it * 512 + tid;
        int ow = e & 63;                             // output f32x4 in row
        int hl = e >> 6;                             // [0,32)
        int odd = ow & 1;
        int i0 = ((2 * ow - 2) & 127) >> 2;          // first window f32x4
        int i1 = ((2 * ow + 3) & 127) >> 2;          // second window f32x4
        const f32x4* u0r = smem + (size_t)hl * 33;
        const f32x4* u1r = smem + (size_t)(32 + hl) * 33;
        f32x4 P  = u0r[i0], Q  = u0r[i1];
        f32x4 Pp = u1r[i0], Qp = u1r[i1];
        float w0 = odd ? P[0]  : P[2],  w1 = odd ? P[1]  : P[3];
        float w2 = odd ? P[2]  : Q[0],  w3 = odd ? P[3]  : Q[1];
        float w4 = odd ? Q[0]  : Q[2],  w5 = odd ? Q[1]  : Q[3];
        float x0 = odd ? Pp[0] : Pp[2], x1 = odd ? Pp[1] : Pp[3];
        float x2 = odd ? Pp[2] : Qp[0], x3 = odd ? Pp[3] : Qp[1];
        float x4 = odd ? Qp[0] : Qp[2], x5 = odd ? Qp[1] : Qp[3];
        f32x4 o;
        o[0] = G01*w3 + G03*w2 + G05*w1 + G07*w0
             + G11*x3 + G13*x2 + G15*x1 + G17*x0;
        o[1] = G00*w4 + G02*w3 + G04*w2 + G06*w1
             + G10*x4 + G12*x3 + G14*x2 + G16*x1;
        o[2] = G01*w4 + G03*w3 + G05*w2 + G07*w1
             + G11*x4 + G13*x3 + G15*x2 + G17*x1;
        o[3] = G00*w5 + G02*w4 + G04*w3 + G06*w2
             + G10*x5 + G12*x4 + G14*x3 + G16*x2;
        f32x4* dst = (f32x4*)(orow_base + (size_t)hl * 256) + ow;
        __builtin_nontemporal_store(o, dst);
    }
}

// Issue one Phase-A batch (10 f32x4 loads) for batch k into named regs P0..P9.
#define AISSUE(P, k) { \
    int x_ = (k) * 16 + xr; int pr_ = x_ / 20; int r_ = x_ - 20 * pr_; \
    int hr_ = h0in + r_; if (hr_ < 0) hr_ += 128; if (hr_ >= 128) hr_ -= 128; \
    const float* lo_ = (pr_ == 0) ? llb : (yb + (size_t)(2 * pr_ - 1) * V); \
    const float* hi_ = yb + (size_t)(2 * pr_) * V; \
    const float* lp_ = lo_ + hr_ * 128 + w4c * 4; \
    const float* hp_ = hi_ + hr_ * 128 + w4c * 4; \
    P##0 = *(const f32x4*)(lp_ + q0); P##1 = *(const f32x4*)(lp_ + q1); \
    P##2 = *(const f32x4*)(lp_ + q2); P##3 = *(const f32x4*)(lp_ + q3); \
    P##4 = *(const f32x4*)(lp_ + q4); \
    P##5 = *(const f32x4*)(hp_ + q0); P##6 = *(const f32x4*)(hp_ + q1); \
    P##7 = *(const f32x4*)(hp_ + q2); P##8 = *(const f32x4*)(hp_ + q3); \
    P##9 = *(const f32x4*)(hp_ + q4); }

// Consume batch k from named regs P0..P9: p0 t -> smem, p1 t -> treg[k].
#define ACONS(P, k) { \
    smem[(k) * 512 + tid] = G01*P##3 + G03*P##2 + G05*P##1 + G07*P##0 \
                          + G11*P##8 + G13*P##7 + G15*P##6 + G17*P##5; \
    treg[k]               = G00*P##4 + G02*P##3 + G04*P##2 + G06*P##1 \
                          + G10*P##9 + G12*P##8 + G14*P##7 + G16*P##6; }

__global__ __launch_bounds__(512) void idwt3_l2_k(
    const float* __restrict__ ll, const float* __restrict__ yh,
    float* __restrict__ out)
{
    constexpr int N = 128;
    constexpr int NN = N * N;
    constexpr size_t V = (size_t)N * N * N;

    __shared__ f32x4 smem[2560];                     // tl[4][20][32]; reused as padded ul

    const int tid  = threadIdx.x;
    const int tile = blockIdx.x;                     // 8 h-tiles
    const int mD   = blockIdx.y;                     // 128 d-pairs
    const int b    = blockIdx.z;                     // 4 batches

    const size_t q0 = (size_t)((mD - 2 + N) & (N - 1)) * NN;
    const size_t q1 = (size_t)((mD - 1 + N) & (N - 1)) * NN;
    const size_t q2 = (size_t)( mD                    ) * NN;
    const size_t q3 = (size_t)((mD + 1) & (N - 1)) * NN;
    const size_t q4 = (size_t)((mD + 2) & (N - 1)) * NN;

    const int h0in = 16 * tile - 2;
    const float* llb = ll + (size_t)b * V;
    const float* yb  = yh + (size_t)b * 7 * V;
    const int xr  = tid >> 5;
    const int w4c = tid & 31;

    f32x4 treg[5];
    f32x4 A0, A1, A2, A3, A4, A5, A6, A7, A8, A9;    // even batches
    f32x4 B0, B1, B2, B3, B4, B5, B6, B7, B8, B9;    // odd batches

    // ---- Phase A: 2-deep pipelined (batches 0..4; 20 loads in flight)
    AISSUE(A, 0);
    AISSUE(B, 1);
    ACONS(A, 0);
    AISSUE(A, 2);
    ACONS(B, 1);
    AISSUE(B, 3);
    ACONS(A, 2);
    AISSUE(A, 4);
    ACONS(B, 3);
    ACONS(A, 4);
    __syncthreads();

    phaseBC_l2(smem, out, b, 2 * mD, tile, tid);
    __syncthreads();

    #pragma unroll
    for (int it = 0; it < 5; ++it) smem[it * 512 + tid] = treg[it];
    __syncthreads();

    phaseBC_l2(smem, out, b, 2 * mD + 1, tile, tid);
}

// ===========================================================================

extern "C" void kernel_launch(void* const* d_in, const int* in_sizes, int n_in,
                              void* d_out, int out_size, void* d_ws, size_t ws_size,
                              hipStream_t stream)
{
    const float* yl  = (const float*)d_in[0];   // (4,1,64,64,64)
    const float* yh1 = (const float*)d_in[1];   // (4,7,128,128,128)
    const float* yh2 = (const float*)d_in[2];   // (4,7,64,64,64)
    float* outf = (float*)d_out;                // (4,1,256,256,256)
    float* ll1  = (float*)d_ws;                 // (4,128,128,128) scratch

    // Level 1 (n=64 -> 128): R7 kernel, 3D grid (best-measured)
    idwt3_fused2_k<6, false><<<dim3(4, 64, 4), 512, 0, stream>>>(yl, yh2, ll1, 0);

    // Level 2 (n=128 -> 256): R12 grid + pipelined Phase A
    idwt3_l2_k<<<dim3(8, 128, 4), 512, 0, stream>>>(ll1, yh1, outf);
}

// Round 17
// 161.191 us; speedup vs baseline: 1.7778x; 1.0986x over previous
//
#include <hip/hip_runtime.h>

typedef float f32x4 __attribute__((ext_vector_type(4)));

// db4 reconstruction filters
#define G00 0.23037781330885523f
#define G01 0.7148465705525415f
#define G02 0.6308807679295904f
#define G03 -0.02798376941698385f
#define G04 -0.18703481171888114f
#define G05 0.030841381835986965f
#define G06 0.032883011666982945f
#define G07 -0.010597401784997278f

#define G10 -0.010597401784997278f
#define G11 -0.032883011666982945f
#define G12 0.030841381835986965f
#define G13 0.18703481171888114f
#define G14 -0.02798376941698385f
#define G15 -0.6308807679295904f
#define G16 0.7148465705525415f
#define G17 -0.23037781330885523f

// ===========================================================================
// Level-1 path (N=64): R7/R12 kernel, unchanged (verified best).
// ===========================================================================
template<int LOGN, bool NT>
__device__ __forceinline__ void phaseBC(f32x4* smem, float* __restrict__ out,
                                        int b, int d, int tile, int tid)
{
    constexpr int N = 1 << LOGN;
    constexpr int N4 = N / 4;
    constexpr int LOGN4 = LOGN - 2;
    constexpr int BELEMS = 2 * 32 * N4;
    constexpr int BITER  = BELEMS / 512;

    f32x4 ureg[BITER];
    #pragma unroll
    for (int it = 0; it < BITER; ++it) {
        int e = it * 512 + tid;
        int w4   = e & (N4 - 1);
        int rest = e >> LOGN4;
        int hl   = rest & 31;
        int qq   = rest >> 5;
        int ml = hl >> 1, pp = hl & 1;
        int ro = ml + pp + 3;
        float b0c = pp ? G00 : G01, b1c = pp ? G02 : G03;
        float b2c = pp ? G04 : G05, b3c = pp ? G06 : G07;
        float d0c = pp ? G10 : G11, d1c = pp ? G12 : G13;
        float d2c = pp ? G14 : G15, d3c = pp ? G16 : G17;
        int s0 = 2 * qq, s1 = s0 + 1;
        ureg[it] = b0c * smem[(s0 * 20 + ro    ) * N4 + w4]
                 + b1c * smem[(s0 * 20 + ro - 1) * N4 + w4]
                 + b2c * smem[(s0 * 20 + ro - 2) * N4 + w4]
                 + b3c * smem[(s0 * 20 + ro - 3) * N4 + w4]
                 + d0c * smem[(s1 * 20 + ro    ) * N4 + w4]
                 + d1c * smem[(s1 * 20 + ro - 1) * N4 + w4]
                 + d2c * smem[(s1 * 20 + ro - 2) * N4 + w4]
                 + d3c * smem[(s1 * 20 + ro - 3) * N4 + w4];
    }
    __syncthreads();
    #pragma unroll
    for (int it = 0; it < BITER; ++it) {
        smem[it * 512 + tid] = ureg[it];
    }
    __syncthreads();

    const float* ulf = (const float*)smem;
    float* orow_base = out + (((size_t)b * (2 * N) + d) * (2 * N) + (size_t)32 * tile) * (2 * N);
    for (int e = tid; e < 32 * (N / 2); e += 512) {
        int mw2 = e & (N / 2 - 1);
        int hl  = e >> (LOGN - 1);
        int mw  = mw2 * 2;
        const float* u0 = ulf + (size_t)hl * N;
        const float* u1 = ulf + (size_t)(32 + hl) * N;
        int mm2 = (mw - 2) & (N - 1), mm1 = (mw - 1) & (N - 1);
        int mp1 = (mw + 1) & (N - 1), mp2 = (mw + 2) & (N - 1), mp3 = (mw + 3) & (N - 1);
        float u0m2 = u0[mm2], u0m1 = u0[mm1], u00 = u0[mw];
        float u0p1 = u0[mp1], u0p2 = u0[mp2], u0p3 = u0[mp3];
        float u1m2 = u1[mm2], u1m1 = u1[mm1], u10 = u1[mw];
        float u1p1 = u1[mp1], u1p2 = u1[mp2], u1p3 = u1[mp3];
        f32x4 o;
        o.x = G01*u0p1 + G03*u00  + G05*u0m1 + G07*u0m2
            + G11*u1p1 + G13*u10  + G15*u1m1 + G17*u1m2;
        o.y = G00*u0p2 + G02*u0p1 + G04*u00  + G06*u0m1
            + G10*u1p2 + G12*u1p1 + G14*u10  + G16*u1m1;
        o.z = G01*u0p2 + G03*u0p1 + G05*u00  + G07*u0m1
            + G11*u1p2 + G13*u1p1 + G15*u10  + G17*u1m1;
        o.w = G00*u0p3 + G02*u0p2 + G04*u0p1 + G06*u00
            + G10*u1p3 + G12*u1p2 + G14*u1p1 + G16*u10;
        f32x4* dst = (f32x4*)(orow_base + (size_t)hl * (2 * N)) + mw2;
        if (NT) __builtin_nontemporal_store(o, dst);
        else    *dst = o;
    }
}

template<int LOGN, bool NT>
__global__ __launch_bounds__(512) void idwt3_fused2_k(
    const float* __restrict__ ll, const float* __restrict__ yh,
    float* __restrict__ out, int b0)
{
    constexpr int N = 1 << LOGN;
    constexpr int N4 = N / 4;
    constexpr int LOGN4 = LOGN - 2;
    constexpr int NN = N * N;
    constexpr size_t V = (size_t)N * N * N;
    constexpr int AELEMS = 4 * 20 * N4;
    constexpr int AITER  = (AELEMS + 511) / 512;

    __shared__ f32x4 smem[AELEMS];

    const int tid  = threadIdx.x;
    const int tile = blockIdx.x;
    const int mD   = blockIdx.y;
    const int b    = b0 + (int)blockIdx.z;

    const size_t q0 = (size_t)((mD - 2 + N) & (N - 1)) * NN;
    const size_t q1 = (size_t)((mD - 1 + N) & (N - 1)) * NN;
    const size_t q2 = (size_t)( mD                    ) * NN;
    const size_t q3 = (size_t)((mD + 1) & (N - 1)) * NN;
    const size_t q4 = (size_t)((mD + 2) & (N - 1)) * NN;

    const int h0in = 16 * tile - 2;
    const float* llb = ll + (size_t)b * V;
    const float* yb  = yh + (size_t)b * 7 * V;

    f32x4 treg[AITER];
    #pragma unroll
    for (int it = 0; it < AITER; ++it) {
        int e = it * 512 + tid;
        if (AELEMS % 512 != 0 && e >= AELEMS) continue;
        int w4 = e & (N4 - 1);
        int x  = e >> LOGN4;
        int pr = x / 20;
        int r  = x - 20 * pr;
        int hr = h0in + r;
        if (hr < 0) hr += N;
        if (hr >= N) hr -= N;
        const float* lo_base = (pr == 0) ? llb : (yb + (size_t)(2 * pr - 1) * V);
        const float* hi_base = yb + (size_t)(2 * pr) * V;
        int off = hr * N + w4 * 4;
        const float* lp = lo_base + off;
        const float* hp = hi_base + off;
        f32x4 Lm2 = *(const f32x4*)(lp + q0);
        f32x4 Lm1 = *(const f32x4*)(lp + q1);
        f32x4 L0c = *(const f32x4*)(lp + q2);
        f32x4 Lp1 = *(const f32x4*)(lp + q3);
        f32x4 Lp2 = *(const f32x4*)(lp + q4);
        f32x4 Hm2 = *(const f32x4*)(hp + q0);
        f32x4 Hm1 = *(const f32x4*)(hp + q1);
        f32x4 H0c = *(const f32x4*)(hp + q2);
        f32x4 Hp1 = *(const f32x4*)(hp + q3);
        f32x4 Hp2 = *(const f32x4*)(hp + q4);
        smem[e] = G01*Lp1 + G03*L0c + G05*Lm1 + G07*Lm2
                + G11*Hp1 + G13*H0c + G15*Hm1 + G17*Hm2;
        treg[it] = G00*Lp2 + G02*Lp1 + G04*L0c + G06*Lm1
                 + G10*Hp2 + G12*Hp1 + G14*H0c + G16*Hm1;
    }
    __syncthreads();

    phaseBC<LOGN, NT>(smem, out, b, 2 * mD, tile, tid);
    __syncthreads();

    #pragma unroll
    for (int it = 0; it < AITER; ++it) {
        int e = it * 512 + tid;
        if (AELEMS % 512 != 0 && e >= AELEMS) continue;
        smem[e] = treg[it];
    }
    __syncthreads();

    phaseBC<LOGN, NT>(smem, out, b, 2 * mD + 1, tile, tid);
}

// ===========================================================================
// Level-2 path (N=128): two adjacent m-values per block (output planes
// 4g..4g+3). Phase A loads the 6-plane union {2g-2..2g+3}: 12 f32x4 loads
// yield 4 t-values (3 loads/plane vs 5 before -> 0.6x cache-read traffic).
// B/C pipeline is the R12-verified code, run 4x with register-stash swaps.
// ===========================================================================
__device__ __forceinline__ void phaseBC_l2(f32x4* smem, float* __restrict__ out,
                                           int b, int d, int tile, int tid)
{
    // ---- Phase B: thread = (s, qq, w4); 4 h-outputs from 12 b128 reads.
    {
        const int w4 = tid & 31;
        const int qq = (tid >> 5) & 1;
        const int s  = tid >> 6;                     // [0,8)
        const f32x4* t0 = smem + ((2 * qq) * 20 + 2 * s) * 32 + w4;   // lo tile
        const f32x4* t1 = t0 + 20 * 32;                               // hi tile
        f32x4 r0 = t0[0],   r1 = t0[32],  r2 = t0[64];
        f32x4 r3 = t0[96],  r4 = t0[128], r5 = t0[160];
        f32x4 e0 = t1[0],   e1 = t1[32],  e2 = t1[64];
        f32x4 e3 = t1[96],  e4 = t1[128], e5 = t1[160];
        f32x4 u0r = G01*r3 + G03*r2 + G05*r1 + G07*r0
                  + G11*e3 + G13*e2 + G15*e1 + G17*e0;
        f32x4 u1r = G00*r4 + G02*r3 + G04*r2 + G06*r1
                  + G10*e4 + G12*e3 + G14*e2 + G16*e1;
        f32x4 u2r = G01*r4 + G03*r3 + G05*r2 + G07*r1
                  + G11*e4 + G13*e3 + G15*e2 + G17*e1;
        f32x4 u3r = G00*r5 + G02*r4 + G04*r3 + G06*r2
                  + G10*e5 + G12*e4 + G14*e3 + G16*e2;
        __syncthreads();                             // all tl reads complete
        f32x4* ub = smem + ((qq * 32 + 4 * s) * 33 + w4);
        ub[0]  = u0r;
        ub[33] = u1r;
        ub[66] = u2r;
        ub[99] = u3r;
    }
    __syncthreads();

    // ---- Phase C: b128 window reads (2 f32x4 per subband) + parity selects.
    float* orow_base = out + (((size_t)b * 256 + d) * 256 + (size_t)32 * tile) * 256;
    #pragma unroll
    for (int it = 0; it < 4; ++it) {
        int e  = it * 512 + tid;
        int ow = e & 63;                             // output f32x4 in row
        int hl = e >> 6;                             // [0,32)
        int odd = ow & 1;
        int i0 = ((2 * ow - 2) & 127) >> 2;          // first window f32x4
        int i1 = ((2 * ow + 3) & 127) >> 2;          // second window f32x4
        const f32x4* u0r = smem + (size_t)hl * 33;
        const f32x4* u1r = smem + (size_t)(32 + hl) * 33;
        f32x4 P  = u0r[i0], Q  = u0r[i1];
        f32x4 Pp = u1r[i0], Qp = u1r[i1];
        float w0 = odd ? P[0]  : P[2],  w1 = odd ? P[1]  : P[3];
        float w2 = odd ? P[2]  : Q[0],  w3 = odd ? P[3]  : Q[1];
        float w4 = odd ? Q[0]  : Q[2],  w5 = odd ? Q[1]  : Q[3];
        float x0 = odd ? Pp[0] : Pp[2], x1 = odd ? Pp[1] : Pp[3];
        float x2 = odd ? Pp[2] : Qp[0], x3 = odd ? Pp[3] : Qp[1];
        float x4 = odd ? Qp[0] : Qp[2], x5 = odd ? Qp[1] : Qp[3];
        f32x4 o;
        o[0] = G01*w3 + G03*w2 + G05*w1 + G07*w0
             + G11*x3 + G13*x2 + G15*x1 + G17*x0;
        o[1] = G00*w4 + G02*w3 + G04*w2 + G06*w1
             + G10*x4 + G12*x3 + G14*x2 + G16*x1;
        o[2] = G01*w4 + G03*w3 + G05*w2 + G07*w1
             + G11*x4 + G13*x3 + G15*x2 + G17*x1;
        o[3] = G00*w5 + G02*w4 + G04*w3 + G06*w2
             + G10*x5 + G12*x4 + G14*x3 + G16*x2;
        f32x4* dst = (f32x4*)(orow_base + (size_t)hl * 256) + ow;
        __builtin_nontemporal_store(o, dst);
    }
}

// One Phase-A batch for batch k: 12 loads (6 planes x lo/hi) -> 4 t-values.
#define ABATCH(k) { \
    int x_ = (k) * 16 + xr; int pr_ = x_ / 20; int r_ = x_ - 20 * pr_; \
    int hr_ = h0in + r_; if (hr_ < 0) hr_ += 128; if (hr_ >= 128) hr_ -= 128; \
    const float* lo_ = (pr_ == 0) ? llb : (yb + (size_t)(2 * pr_ - 1) * V); \
    const float* hi_ = yb + (size_t)(2 * pr_) * V; \
    const float* lp_ = lo_ + hr_ * 128 + w4c * 4; \
    const float* hp_ = hi_ + hr_ * 128 + w4c * 4; \
    f32x4 L0 = *(const f32x4*)(lp_ + q0), L1 = *(const f32x4*)(lp_ + q1); \
    f32x4 L2 = *(const f32x4*)(lp_ + q2), L3 = *(const f32x4*)(lp_ + q3); \
    f32x4 L4 = *(const f32x4*)(lp_ + q4), L5 = *(const f32x4*)(lp_ + q5); \
    f32x4 H0 = *(const f32x4*)(hp_ + q0), H1 = *(const f32x4*)(hp_ + q1); \
    f32x4 H2 = *(const f32x4*)(hp_ + q2), H3 = *(const f32x4*)(hp_ + q3); \
    f32x4 H4 = *(const f32x4*)(hp_ + q4), H5 = *(const f32x4*)(hp_ + q5); \
    smem[(k) * 512 + tid] = G01*L3 + G03*L2 + G05*L1 + G07*L0 \
                          + G11*H3 + G13*H2 + G15*H1 + G17*H0; \
    tA1[k] = G00*L4 + G02*L3 + G04*L2 + G06*L1 \
           + G10*H4 + G12*H3 + G14*H2 + G16*H1; \
    tB0[k] = G01*L4 + G03*L3 + G05*L2 + G07*L1 \
           + G11*H4 + G13*H3 + G15*H2 + G17*H1; \
    tB1[k] = G00*L5 + G02*L4 + G04*L3 + G06*L2 \
           + G10*H5 + G12*H4 + G14*H3 + G16*H2; }

#define TSWAP(tarr) { \
    _Pragma("unroll") \
    for (int it_ = 0; it_ < 5; ++it_) smem[it_ * 512 + tid] = (tarr)[it_]; }

__global__ __launch_bounds__(512) void idwt3_l2q_k(
    const float* __restrict__ ll, const float* __restrict__ yh,
    float* __restrict__ out)
{
    constexpr int N = 128;
    constexpr int NN = N * N;
    constexpr size_t V = (size_t)N * N * N;

    __shared__ f32x4 smem[2560];                 // tl[4][20][32]; reused as padded ul

    const int tid  = threadIdx.x;
    const int tile = blockIdx.x;                 // 8 h-tiles
    const int g    = blockIdx.y;                 // 64 m-value pairs (mA=2g, mB=2g+1)
    const int b    = blockIdx.z;                 // 4 batches

    // 6-plane union {2g-2 .. 2g+3} (wrapped)
    const size_t q0 = (size_t)((2 * g - 2 + N) & (N - 1)) * NN;
    const size_t q1 = (size_t)((2 * g - 1 + N) & (N - 1)) * NN;
    const size_t q2 = (size_t)( 2 * g                    ) * NN;
    const size_t q3 = (size_t)((2 * g + 1) & (N - 1)) * NN;
    const size_t q4 = (size_t)((2 * g + 2) & (N - 1)) * NN;
    const size_t q5 = (size_t)((2 * g + 3) & (N - 1)) * NN;

    const int h0in = 16 * tile - 2;
    const float* llb = ll + (size_t)b * V;
    const float* yb  = yh + (size_t)b * 7 * V;
    const int xr  = tid >> 5;
    const int w4c = tid & 31;

    f32x4 tA1[5], tB0[5], tB1[5];                // register stashes (static idx)

    ABATCH(0); ABATCH(1); ABATCH(2); ABATCH(3); ABATCH(4);
    __syncthreads();

    phaseBC_l2(smem, out, b, 4 * g + 0, tile, tid);
    __syncthreads();
    TSWAP(tA1);
    __syncthreads();
    phaseBC_l2(smem, out, b, 4 * g + 1, tile, tid);
    __syncthreads();
    TSWAP(tB0);
    __syncthreads();
    phaseBC_l2(smem, out, b, 4 * g + 2, tile, tid);
    __syncthreads();
    TSWAP(tB1);
    __syncthreads();
    phaseBC_l2(smem, out, b, 4 * g + 3, tile, tid);
}

// ===========================================================================

extern "C" void kernel_launch(void* const* d_in, const int* in_sizes, int n_in,
                              void* d_out, int out_size, void* d_ws, size_t ws_size,
                              hipStream_t stream)
{
    const float* yl  = (const float*)d_in[0];   // (4,1,64,64,64)
    const float* yh1 = (const float*)d_in[1];   // (4,7,128,128,128)
    const float* yh2 = (const float*)d_in[2];   // (4,7,64,64,64)
    float* outf = (float*)d_out;                // (4,1,256,256,256)
    float* ll1  = (float*)d_ws;                 // (4,128,128,128) scratch

    // Level 1 (n=64 -> 128): R7 kernel, 3D grid (best-measured)
    idwt3_fused2_k<6, false><<<dim3(4, 64, 4), 512, 0, stream>>>(yl, yh2, ll1, 0);

    // Level 2 (n=128 -> 256): quad-plane kernel, 2048 blocks
    idwt3_l2q_k<<<dim3(8, 64, 4), 512, 0, stream>>>(ll1, yh1, outf);
}